// Round 1
// baseline (4345.735 us; speedup 1.0000x reference)
//
#include <hip/hip_runtime.h>
#include <hip/hip_bf16.h>
#include <cstdio>

// Problem dims
#define T_  128
#define B_  64
#define TB  8192      // T_*B_
#define N_  24
#define D_  256
#define H_  8
#define F_  32
#define ND  6144      // N_*D_
#define HF  256       // H_*F_
#define HNF 6144      // H_*N_*F_
#define COLS 768      // HF cols for each of K,V,Q concatenated
#define MT  64        // rows (tb) per block in proj kernel

__device__ __forceinline__ unsigned short f2b(float f) {
    unsigned int u = __float_as_uint(f);
    return (unsigned short)((u + 0x7FFFu + ((u >> 16) & 1u)) >> 16);
}
__device__ __forceinline__ float b2f(unsigned short s) {
    return __uint_as_float(((unsigned int)s) << 16);
}

// ---------------- Phase 1: projections (fp32 vector FMA baseline) ----------------
// grid (TB/MT, N_), block 256. Computes K,V,Q for 64 tokens x one joint n,
// stores bf16 into workspace laid out [tb][h][n][f].
__global__ __launch_bounds__(256) void proj_kernel(
    const float* __restrict__ x,
    const float* __restrict__ Wk, const float* __restrict__ bk,
    const float* __restrict__ Wv, const float* __restrict__ bv,
    const float* __restrict__ Wq, const float* __restrict__ bq,
    unsigned short* __restrict__ kb, unsigned short* __restrict__ vb,
    unsigned short* __restrict__ qb)
{
    const int n   = blockIdx.y;
    const int tb0 = blockIdx.x * MT;
    const int tid = threadIdx.x;

    __shared__ __align__(16) float As[MT][D_ + 4];  // +4 pad

    // Load A tile: 64 rows x 256 f32, coalesced float4
    for (int i = tid; i < MT * (D_ / 4); i += 256) {
        const int row = i >> 6;   // /64 float4s per row
        const int d4  = i & 63;
        const float4 v4 = *reinterpret_cast<const float4*>(
            &x[(size_t)(tb0 + row) * ND + n * D_ + d4 * 4]);
        *reinterpret_cast<float4*>(&As[row][d4 * 4]) = v4;
    }
    __syncthreads();

    const int ty = tid >> 4;   // 0..15
    const int tx = tid & 15;   // 0..15
    const int r0 = ty * 4;     // 4 rows per thread

    for (int cc = 0; cc < 12; ++cc) {
        const int col0 = cc * 64 + tx * 4;     // 4 cols per thread, same kind
        const int kind = col0 >> 8;            // 0=K,1=V,2=Q
        const float* Brow[4];
        float bias[4];
        #pragma unroll
        for (int j = 0; j < 4; ++j) {
            const int col = col0 + j;
            const int c   = col & 255;
            if (kind == 0)      { Brow[j] = Wk + (size_t)c * D_; bias[j] = bk[c]; }
            else if (kind == 1) { Brow[j] = Wv + (size_t)c * D_; bias[j] = bv[c]; }
            else {
                const int h = c >> 5, f = c & 31;
                const size_t wi = ((size_t)(h * N_ + n) * F_ + f);
                Brow[j] = Wq + wi * D_;
                bias[j] = bq[wi];
            }
        }

        float acc[4][4] = {};
        #pragma unroll 4
        for (int k4 = 0; k4 < 64; ++k4) {
            float4 a[4], b[4];
            #pragma unroll
            for (int i = 0; i < 4; ++i)
                a[i] = *reinterpret_cast<const float4*>(&As[r0 + i][k4 * 4]);
            #pragma unroll
            for (int j = 0; j < 4; ++j)
                b[j] = *reinterpret_cast<const float4*>(Brow[j] + k4 * 4);
            #pragma unroll
            for (int i = 0; i < 4; ++i)
                #pragma unroll
                for (int j = 0; j < 4; ++j)
                    acc[i][j] = fmaf(a[i].x, b[j].x,
                                fmaf(a[i].y, b[j].y,
                                fmaf(a[i].z, b[j].z,
                                fmaf(a[i].w, b[j].w, acc[i][j]))));
        }

        // Store 4x4 as bf16, packed 4-wide (f0..f0+3 never crosses a head)
        const int hf = col0 & 255;
        const int h  = hf >> 5;
        const int f0 = hf & 31;
        unsigned short* dst = (kind == 0) ? kb : (kind == 1) ? vb : qb;
        #pragma unroll
        for (int i = 0; i < 4; ++i) {
            const int tb = tb0 + r0 + i;
            ushort4 pk;
            pk.x = f2b(acc[i][0] + bias[0]);
            pk.y = f2b(acc[i][1] + bias[1]);
            pk.z = f2b(acc[i][2] + bias[2]);
            pk.w = f2b(acc[i][3] + bias[3]);
            *reinterpret_cast<ushort4*>(
                &dst[(size_t)tb * HNF + h * (N_ * F_) + n * F_ + f0]) = pk;
        }
    }
}

// ---------------- Phase 2: attention per (t,b) ----------------
// grid TB, block 256. Reads bf16 q/k/v [h][n][f], fp32 scores/softmax/PV.
__global__ __launch_bounds__(256) void attn_kernel(
    const unsigned short* __restrict__ kb,
    const unsigned short* __restrict__ vb,
    const unsigned short* __restrict__ qb,
    float* __restrict__ out)
{
    const int tb  = blockIdx.x;
    const int tid = threadIdx.x;

    __shared__ __align__(16) unsigned short qs[HNF];
    __shared__ __align__(16) unsigned short ks[HNF];
    __shared__ __align__(16) unsigned short vs[HNF];
    __shared__ float sc[H_ * N_ * N_];   // 4608 floats

    const size_t base = (size_t)tb * HNF;
    for (int i = tid; i < HNF / 8; i += 256) {
        reinterpret_cast<uint4*>(qs)[i] = reinterpret_cast<const uint4*>(qb + base)[i];
        reinterpret_cast<uint4*>(ks)[i] = reinterpret_cast<const uint4*>(kb + base)[i];
        reinterpret_cast<uint4*>(vs)[i] = reinterpret_cast<const uint4*>(vb + base)[i];
    }
    __syncthreads();

    // scores[h][nq][m] = q . k / sqrt(F)
    for (int idx = tid; idx < H_ * N_ * N_; idx += 256) {
        const int h  = idx / (N_ * N_);
        const int r  = idx % (N_ * N_);
        const int nq = r / N_;
        const int m  = r % N_;
        const unsigned short* qp = &qs[(h * N_ + nq) * F_];
        const unsigned short* kp = &ks[(h * N_ + m) * F_];
        float s = 0.f;
        #pragma unroll
        for (int f = 0; f < F_; ++f) s = fmaf(b2f(qp[f]), b2f(kp[f]), s);
        sc[(h * N_ + nq) * N_ + m] = s * 0.17677669529663687f;  // 1/sqrt(32)
    }
    __syncthreads();

    // softmax over m (one row per thread, 192 rows)
    if (tid < H_ * N_) {
        float* row = &sc[tid * N_];
        float mx = row[0];
        #pragma unroll
        for (int m = 1; m < N_; ++m) mx = fmaxf(mx, row[m]);
        float sum = 0.f;
        #pragma unroll
        for (int m = 0; m < N_; ++m) { float e = __expf(row[m] - mx); row[m] = e; sum += e; }
        const float inv = 1.f / sum;
        #pragma unroll
        for (int m = 0; m < N_; ++m) row[m] *= inv;
    }
    __syncthreads();

    // out[tb, nq*256 + h*32 + f] = sum_m attn[h][nq][m] * v[h][m][f]
    for (int idx = tid; idx < HNF; idx += 256) {
        const int h  = idx / (N_ * F_);
        const int r  = idx % (N_ * F_);
        const int nq = r / F_;
        const int f  = r % F_;
        const float* arow = &sc[(h * N_ + nq) * N_];
        float s = 0.f;
        #pragma unroll
        for (int m = 0; m < N_; ++m)
            s = fmaf(arow[m], b2f(vs[(h * N_ + m) * F_ + f]), s);
        out[(size_t)tb * ND + nq * D_ + h * F_ + f] = s;
    }
}

extern "C" void kernel_launch(void* const* d_in, const int* in_sizes, int n_in,
                              void* d_out, int out_size, void* d_ws, size_t ws_size,
                              hipStream_t stream) {
    const float* x  = (const float*)d_in[0];
    const float* Wk = (const float*)d_in[1];
    const float* bk = (const float*)d_in[2];
    const float* Wv = (const float*)d_in[3];
    const float* bv = (const float*)d_in[4];
    const float* Wq = (const float*)d_in[5];
    const float* bq = (const float*)d_in[6];
    float* out = (float*)d_out;

    const size_t qkv_elems = (size_t)TB * HNF;        // 50,331,648
    const size_t need = qkv_elems * 2ull * 3ull;      // 302 MB bf16 q/k/v
    if (ws_size < need) {
        fprintf(stderr, "kernel_launch: ws too small: %zu < %zu\n", ws_size, need);
    }
    unsigned short* kb = (unsigned short*)d_ws;
    unsigned short* vb = kb + qkv_elems;
    unsigned short* qb = vb + qkv_elems;

    proj_kernel<<<dim3(TB / MT, N_), 256, 0, stream>>>(x, Wk, bk, Wv, bv, Wq, bq, kb, vb, qb);
    attn_kernel<<<TB, 256, 0, stream>>>(kb, vb, qb, out);
}

// Round 2
// 575.154 us; speedup vs baseline: 7.5558x; 7.5558x over previous
//
#include <hip/hip_runtime.h>
#include <hip/hip_bf16.h>
#include <cstdio>

#define T_  128
#define B_  64
#define TB  8192
#define N_  24
#define D_  256
#define H_  8
#define F_  32
#define ND  6144      // N_*D_
#define HNF 6144      // H_*N_*F_
#define NCOL 768      // K|V|Q columns per joint

typedef unsigned short ushort_t;
typedef __attribute__((ext_vector_type(8))) short bf16x8;
typedef __attribute__((ext_vector_type(4))) float f32x4;

__device__ __forceinline__ unsigned short f2b(float f) {
    unsigned int u = __float_as_uint(f);
    return (unsigned short)((u + 0x7FFFu + ((u >> 16) & 1u)) >> 16);
}
__device__ __forceinline__ float b2f(unsigned short s) {
    return __uint_as_float(((unsigned int)s) << 16);
}

__device__ __forceinline__ void gl_lds16(const void* g, void* l) {
    __builtin_amdgcn_global_load_lds(
        (const __attribute__((address_space(1))) unsigned int*)g,
        (__attribute__((address_space(3))) unsigned int*)l, 16, 0, 0);
}

// ---------- prep: weights -> bf16 in LDS-image layout [n][kt][ch][col][8] ----------
__global__ __launch_bounds__(256) void prep_weights(
    const float* __restrict__ Wk, const float* __restrict__ Wv,
    const float* __restrict__ Wq, ushort_t* __restrict__ Bprep)
{
    const int idx = blockIdx.x * 256 + threadIdx.x;   // 0 .. 24*8*4*768-1
    if (idx >= 24 * 8 * 4 * 768) return;
    const int col = idx % 768;
    const int ch  = (idx / 768) % 4;
    const int kt  = (idx / 3072) % 8;
    const int n   = idx / 24576;
    const int d0  = kt * 32 + ch * 8;
    const int c   = col & 255;
    const float* src;
    if (col < 256)      src = Wk + (size_t)c * 256 + d0;
    else if (col < 512) src = Wv + (size_t)c * 256 + d0;
    else {
        const int h = c >> 5, f = c & 31;
        src = Wq + ((size_t)(h * 24 + n) * 32 + f) * 256 + d0;
    }
    __align__(16) ushort_t out[8];
    #pragma unroll
    for (int j = 0; j < 8; ++j) out[j] = f2b(src[j]);
    ushort_t* dst = Bprep + ((size_t)(n * 8 + kt)) * 24576 + ch * 6144 + col * 8;
    *reinterpret_cast<uint4*>(dst) = *reinterpret_cast<const uint4*>(out);
}

__global__ __launch_bounds__(256) void prep_bias(
    const float* __restrict__ bk, const float* __restrict__ bv,
    const float* __restrict__ bq, float* __restrict__ biasp)
{
    const int idx = blockIdx.x * 256 + threadIdx.x;   // 0..24*768-1
    if (idx >= 24 * 768) return;
    const int col = idx % 768, n = idx / 768;
    const int c = col & 255;
    float v;
    if (col < 256)      v = bk[c];
    else if (col < 512) v = bv[c];
    else { const int h = c >> 5, f = c & 31; v = bq[(h * 24 + n) * 32 + f]; }
    biasp[n * 768 + col] = v;
}

// ---------- proj: MFMA GEMM, BM=32 x BN=768, BK=32, split-x hi/lo ----------
__global__ __launch_bounds__(256, 2) void proj_mfma(
    const float* __restrict__ x,
    const ushort_t* __restrict__ Bprep,
    const float* __restrict__ biasp,
    ushort_t* __restrict__ kb, ushort_t* __restrict__ vb, ushort_t* __restrict__ qb)
{
    const int mblk = blockIdx.x;        // 0..255
    const int n    = blockIdx.y;        // 0..23
    const int tb0  = mblk * 32;
    const int tid  = threadIdx.x;
    const int wid  = tid >> 6;
    const int lane = tid & 63;

    __shared__ __align__(16) ushort_t smem[26624];   // 52 KiB
    ushort_t (*Bs)[768][8]  = (ushort_t(*)[768][8])smem;            // [4][768][8]
    ushort_t (*Ahi)[32][8]  = (ushort_t(*)[32][8])(smem + 24576);   // [4][32][8]
    ushort_t (*Alo)[32][8]  = (ushort_t(*)[32][8])(smem + 24576 + 1024);

    f32x4 acc[2][12];
    #pragma unroll
    for (int m = 0; m < 2; ++m)
        #pragma unroll
        for (int nf = 0; nf < 12; ++nf)
            acc[m][nf] = (f32x4){0.f, 0.f, 0.f, 0.f};

    const char* Bsrc = (const char*)(Bprep + (size_t)n * 8 * 24576);
    const int arow = tid >> 3;     // 0..31
    const int aq   = tid & 7;      // float4 within 32-k tile
    const float* xsrc = x + (size_t)(tb0 + arow) * ND + n * D_ + aq * 4;
    const int ach = aq >> 1, ahalf = (aq & 1) * 4;

    const int fr = lane & 15, fq = lane >> 4;

    for (int kt = 0; kt < 8; ++kt) {
        // --- A: load fp32, split hi/lo bf16, write LDS ---
        const float4 xa = *reinterpret_cast<const float4*>(xsrc + kt * 32);
        ushort4 hi, lo;
        hi.x = f2b(xa.x); lo.x = f2b(xa.x - b2f(hi.x));
        hi.y = f2b(xa.y); lo.y = f2b(xa.y - b2f(hi.y));
        hi.z = f2b(xa.z); lo.z = f2b(xa.z - b2f(hi.z));
        hi.w = f2b(xa.w); lo.w = f2b(xa.w - b2f(hi.w));
        *reinterpret_cast<ushort4*>(&Ahi[ach][arow][ahalf]) = hi;
        *reinterpret_cast<ushort4*>(&Alo[ach][arow][ahalf]) = lo;

        // --- B: 48 KiB via global_load_lds width 16 (linear dest) ---
        const char* bkt = Bsrc + (size_t)kt * 49152;
        #pragma unroll
        for (int i = 0; i < 12; ++i) {
            const int off = (i * 4 + wid) * 1024;
            gl_lds16(bkt + off + lane * 16, (char*)smem + off);
        }
        __syncthreads();   // drains vmcnt+lgkmcnt

        const bf16x8 ahi0 = *(const bf16x8*)&Ahi[fq][fr][0];
        const bf16x8 ahi1 = *(const bf16x8*)&Ahi[fq][16 + fr][0];
        const bf16x8 alo0 = *(const bf16x8*)&Alo[fq][fr][0];
        const bf16x8 alo1 = *(const bf16x8*)&Alo[fq][16 + fr][0];
        #pragma unroll
        for (int nf = 0; nf < 12; ++nf) {
            const bf16x8 b = *(const bf16x8*)&Bs[fq][wid * 192 + nf * 16 + fr][0];
            acc[0][nf] = __builtin_amdgcn_mfma_f32_16x16x32_bf16(ahi0, b, acc[0][nf], 0, 0, 0);
            acc[1][nf] = __builtin_amdgcn_mfma_f32_16x16x32_bf16(ahi1, b, acc[1][nf], 0, 0, 0);
            acc[0][nf] = __builtin_amdgcn_mfma_f32_16x16x32_bf16(alo0, b, acc[0][nf], 0, 0, 0);
            acc[1][nf] = __builtin_amdgcn_mfma_f32_16x16x32_bf16(alo1, b, acc[1][nf], 0, 0, 0);
        }
        __syncthreads();
    }

    // --- epilogue: bias + bf16, transpose through LDS, coalesced 16B stores ---
    ushort_t* outs = smem;   // [32][768]
    #pragma unroll
    for (int nf = 0; nf < 12; ++nf) {
        const int col  = wid * 192 + nf * 16 + fr;
        const float bs = biasp[n * 768 + col];
        #pragma unroll
        for (int m = 0; m < 2; ++m)
            #pragma unroll
            for (int r = 0; r < 4; ++r)
                outs[(m * 16 + fq * 4 + r) * 768 + col] = f2b(acc[m][nf][r] + bs);
    }
    __syncthreads();

    #pragma unroll
    for (int i = 0; i < 12; ++i) {
        const int id   = tid + i * 256;       // 0..3071 chunks of 8 ushorts
        const int row  = id / 96;
        const int col0 = (id % 96) * 8;
        const int kind = col0 >> 8;
        const int c    = col0 & 255;
        const int h    = c >> 5, f0 = c & 31;
        ushort_t* dst = (kind == 0) ? kb : (kind == 1) ? vb : qb;
        const size_t di = (size_t)(tb0 + row) * HNF + h * (N_ * F_) + n * F_ + f0;
        *reinterpret_cast<uint4*>(&dst[di]) =
            *reinterpret_cast<const uint4*>(&outs[row * 768 + col0]);
    }
}

// ---------------- attention per (t,b) ----------------
__global__ __launch_bounds__(256) void attn_kernel(
    const ushort_t* __restrict__ kb,
    const ushort_t* __restrict__ vb,
    const ushort_t* __restrict__ qb,
    float* __restrict__ out)
{
    const int tb  = blockIdx.x;
    const int tid = threadIdx.x;

    __shared__ __align__(16) ushort_t qs[HNF];
    __shared__ __align__(16) ushort_t ks[HNF];
    __shared__ __align__(16) ushort_t vs[HNF];
    __shared__ float sc[H_ * N_ * N_];

    const size_t base = (size_t)tb * HNF;
    for (int i = tid; i < HNF / 8; i += 256) {
        reinterpret_cast<uint4*>(qs)[i] = reinterpret_cast<const uint4*>(qb + base)[i];
        reinterpret_cast<uint4*>(ks)[i] = reinterpret_cast<const uint4*>(kb + base)[i];
        reinterpret_cast<uint4*>(vs)[i] = reinterpret_cast<const uint4*>(vb + base)[i];
    }
    __syncthreads();

    for (int idx = tid; idx < H_ * N_ * N_; idx += 256) {
        const int h  = idx / (N_ * N_);
        const int r  = idx % (N_ * N_);
        const int nq = r / N_;
        const int m  = r % N_;
        const ushort_t* qp = &qs[(h * N_ + nq) * F_];
        const ushort_t* kp = &ks[(h * N_ + m) * F_];
        float s = 0.f;
        #pragma unroll
        for (int f = 0; f < F_; ++f) s = fmaf(b2f(qp[f]), b2f(kp[f]), s);
        sc[(h * N_ + nq) * N_ + m] = s * 0.17677669529663687f;
    }
    __syncthreads();

    if (tid < H_ * N_) {
        float* row = &sc[tid * N_];
        float mx = row[0];
        #pragma unroll
        for (int m = 1; m < N_; ++m) mx = fmaxf(mx, row[m]);
        float sum = 0.f;
        #pragma unroll
        for (int m = 0; m < N_; ++m) { float e = __expf(row[m] - mx); row[m] = e; sum += e; }
        const float inv = 1.f / sum;
        #pragma unroll
        for (int m = 0; m < N_; ++m) row[m] *= inv;
    }
    __syncthreads();

    for (int idx = tid; idx < HNF; idx += 256) {
        const int h  = idx / (N_ * F_);
        const int r  = idx % (N_ * F_);
        const int nq = r / F_;
        const int f  = r % F_;
        const float* arow = &sc[(h * N_ + nq) * N_];
        float s = 0.f;
        #pragma unroll
        for (int m = 0; m < N_; ++m)
            s = fmaf(arow[m], b2f(vs[(h * N_ + m) * F_ + f]), s);
        out[(size_t)tb * ND + nq * D_ + h * F_ + f] = s;
    }
}

extern "C" void kernel_launch(void* const* d_in, const int* in_sizes, int n_in,
                              void* d_out, int out_size, void* d_ws, size_t ws_size,
                              hipStream_t stream) {
    const float* x  = (const float*)d_in[0];
    const float* Wk = (const float*)d_in[1];
    const float* bk = (const float*)d_in[2];
    const float* Wv = (const float*)d_in[3];
    const float* bv = (const float*)d_in[4];
    const float* Wq = (const float*)d_in[5];
    const float* bq = (const float*)d_in[6];
    float* out = (float*)d_out;

    // ws: q/k/v bf16 buffers (302 MB, proven to fit)
    const size_t qkv_elems = (size_t)TB * HNF;
    const size_t need = qkv_elems * 2ull * 3ull;
    if (ws_size < need) fprintf(stderr, "ws too small: %zu < %zu\n", ws_size, need);
    ushort_t* kb = (ushort_t*)d_ws;
    ushort_t* vb = kb + qkv_elems;
    ushort_t* qb = vb + qkv_elems;

    // Bprep (9.44 MB) + biasp (73 KB) live at the head of d_out; the attention
    // kernel later overwrites every element of d_out, stream-ordered after proj.
    ushort_t* Bprep = (ushort_t*)d_out;
    float*    biasp = (float*)((char*)d_out + 24ull * 8 * 24576 * 2);

    prep_weights<<<(24 * 8 * 4 * 768 + 255) / 256, 256, 0, stream>>>(Wk, Wv, Wq, Bprep);
    prep_bias<<<(24 * 768 + 255) / 256, 256, 0, stream>>>(bk, bv, bq, biasp);
    proj_mfma<<<dim3(256, 24), 256, 0, stream>>>(x, Bprep, biasp, kb, vb, qb);
    attn_kernel<<<TB, 256, 0, stream>>>(kb, vb, qb, out);
}

// Round 3
// 407.936 us; speedup vs baseline: 10.6530x; 1.4099x over previous
//
#include <hip/hip_runtime.h>
#include <hip/hip_bf16.h>
#include <cstdio>

#define T_  128
#define B_  64
#define TB  8192
#define N_  24
#define D_  256
#define H_  8
#define F_  32
#define ND  6144      // N_*D_
#define HNF 6144      // H_*N_*F_

typedef unsigned short ushort_t;
typedef __attribute__((ext_vector_type(8))) short bf16x8;
typedef __attribute__((ext_vector_type(4))) float f32x4;

__device__ __forceinline__ unsigned short f2b(float f) {
    unsigned int u = __float_as_uint(f);
    return (unsigned short)((u + 0x7FFFu + ((u >> 16) & 1u)) >> 16);
}
__device__ __forceinline__ float b2f(unsigned short s) {
    return __uint_as_float(((unsigned int)s) << 16);
}

__device__ __forceinline__ void gl_lds16(const void* g, void* l) {
    __builtin_amdgcn_global_load_lds(
        (const __attribute__((address_space(1))) unsigned int*)g,
        (__attribute__((address_space(3))) unsigned int*)l, 16, 0, 0);
}

// ---------- prep: weights -> bf16 in LDS-image layout [n][kt][ch][col][8] ----------
__global__ __launch_bounds__(256) void prep_weights(
    const float* __restrict__ Wk, const float* __restrict__ Wv,
    const float* __restrict__ Wq, ushort_t* __restrict__ Bprep)
{
    const int idx = blockIdx.x * 256 + threadIdx.x;
    if (idx >= 24 * 8 * 4 * 768) return;
    const int col = idx % 768;
    const int ch  = (idx / 768) % 4;
    const int kt  = (idx / 3072) % 8;
    const int n   = idx / 24576;
    const int d0  = kt * 32 + ch * 8;
    const int c   = col & 255;
    const float* src;
    if (col < 256)      src = Wk + (size_t)c * 256 + d0;
    else if (col < 512) src = Wv + (size_t)c * 256 + d0;
    else {
        const int h = c >> 5, f = c & 31;
        src = Wq + ((size_t)(h * 24 + n) * 32 + f) * 256 + d0;
    }
    __align__(16) ushort_t out[8];
    #pragma unroll
    for (int j = 0; j < 8; ++j) out[j] = f2b(src[j]);
    ushort_t* dst = Bprep + ((size_t)(n * 8 + kt)) * 24576 + ch * 6144 + col * 8;
    *reinterpret_cast<uint4*>(dst) = *reinterpret_cast<const uint4*>(out);
}

__global__ __launch_bounds__(256) void prep_bias(
    const float* __restrict__ bk, const float* __restrict__ bv,
    const float* __restrict__ bq, float* __restrict__ biasp)
{
    const int idx = blockIdx.x * 256 + threadIdx.x;
    if (idx >= 24 * 768) return;
    const int col = idx % 768, n = idx / 768;
    const int c = col & 255;
    float v;
    if (col < 256)      v = bk[c];
    else if (col < 512) v = bv[c];
    else { const int h = c >> 5, f = c & 31; v = bq[(h * 24 + n) * 32 + f]; }
    biasp[n * 768 + col] = v;
}

// ---------- proj: MFMA GEMM, BM=32 x BN=768, BK=32, split-x hi/lo ----------
__global__ __launch_bounds__(256, 2) void proj_mfma(
    const float* __restrict__ x,
    const ushort_t* __restrict__ Bprep,
    const float* __restrict__ biasp,
    ushort_t* __restrict__ kb, ushort_t* __restrict__ vb, ushort_t* __restrict__ qb)
{
    const int mblk = blockIdx.x;
    const int n    = blockIdx.y;
    const int tb0  = mblk * 32;
    const int tid  = threadIdx.x;
    const int wid  = tid >> 6;
    const int lane = tid & 63;

    __shared__ __align__(16) ushort_t smem[26624];
    ushort_t (*Bs)[768][8]  = (ushort_t(*)[768][8])smem;
    ushort_t (*Ahi)[32][8]  = (ushort_t(*)[32][8])(smem + 24576);
    ushort_t (*Alo)[32][8]  = (ushort_t(*)[32][8])(smem + 24576 + 1024);

    f32x4 acc[2][12];
    #pragma unroll
    for (int m = 0; m < 2; ++m)
        #pragma unroll
        for (int nf = 0; nf < 12; ++nf)
            acc[m][nf] = (f32x4){0.f, 0.f, 0.f, 0.f};

    const char* Bsrc = (const char*)(Bprep + (size_t)n * 8 * 24576);
    const int arow = tid >> 3;
    const int aq   = tid & 7;
    const float* xsrc = x + (size_t)(tb0 + arow) * ND + n * D_ + aq * 4;
    const int ach = aq >> 1, ahalf = (aq & 1) * 4;

    const int fr = lane & 15, fq = lane >> 4;

    for (int kt = 0; kt < 8; ++kt) {
        const float4 xa = *reinterpret_cast<const float4*>(xsrc + kt * 32);
        ushort4 hi, lo;
        hi.x = f2b(xa.x); lo.x = f2b(xa.x - b2f(hi.x));
        hi.y = f2b(xa.y); lo.y = f2b(xa.y - b2f(hi.y));
        hi.z = f2b(xa.z); lo.z = f2b(xa.z - b2f(hi.z));
        hi.w = f2b(xa.w); lo.w = f2b(xa.w - b2f(hi.w));
        *reinterpret_cast<ushort4*>(&Ahi[ach][arow][ahalf]) = hi;
        *reinterpret_cast<ushort4*>(&Alo[ach][arow][ahalf]) = lo;

        const char* bkt = Bsrc + (size_t)kt * 49152;
        #pragma unroll
        for (int i = 0; i < 12; ++i) {
            const int off = (i * 4 + wid) * 1024;
            gl_lds16(bkt + off + lane * 16, (char*)smem + off);
        }
        __syncthreads();

        const bf16x8 ahi0 = *(const bf16x8*)&Ahi[fq][fr][0];
        const bf16x8 ahi1 = *(const bf16x8*)&Ahi[fq][16 + fr][0];
        const bf16x8 alo0 = *(const bf16x8*)&Alo[fq][fr][0];
        const bf16x8 alo1 = *(const bf16x8*)&Alo[fq][16 + fr][0];
        #pragma unroll
        for (int nf = 0; nf < 12; ++nf) {
            const bf16x8 b = *(const bf16x8*)&Bs[fq][wid * 192 + nf * 16 + fr][0];
            acc[0][nf] = __builtin_amdgcn_mfma_f32_16x16x32_bf16(ahi0, b, acc[0][nf], 0, 0, 0);
            acc[1][nf] = __builtin_amdgcn_mfma_f32_16x16x32_bf16(ahi1, b, acc[1][nf], 0, 0, 0);
            acc[0][nf] = __builtin_amdgcn_mfma_f32_16x16x32_bf16(alo0, b, acc[0][nf], 0, 0, 0);
            acc[1][nf] = __builtin_amdgcn_mfma_f32_16x16x32_bf16(alo1, b, acc[1][nf], 0, 0, 0);
        }
        __syncthreads();
    }

    ushort_t* outs = smem;
    #pragma unroll
    for (int nf = 0; nf < 12; ++nf) {
        const int col  = wid * 192 + nf * 16 + fr;
        const float bs = biasp[n * 768 + col];
        #pragma unroll
        for (int m = 0; m < 2; ++m)
            #pragma unroll
            for (int r = 0; r < 4; ++r)
                outs[(m * 16 + fq * 4 + r) * 768 + col] = f2b(acc[m][nf][r] + bs);
    }
    __syncthreads();

    #pragma unroll
    for (int i = 0; i < 12; ++i) {
        const int id   = tid + i * 256;
        const int row  = id / 96;
        const int col0 = (id % 96) * 8;
        const int kind = col0 >> 8;
        const int c    = col0 & 255;
        const int h    = c >> 5, f0 = c & 31;
        ushort_t* dst = (kind == 0) ? kb : (kind == 1) ? vb : qb;
        const size_t di = (size_t)(tb0 + row) * HNF + h * (N_ * F_) + n * F_ + f0;
        *reinterpret_cast<uint4*>(&dst[di]) =
            *reinterpret_cast<const uint4*>(&outs[row * 768 + col0]);
    }
}

// ---------------- attention v2: MFMA, one wave per tb, barrier-free ----------------
// XOR chunk-swizzle for 64B-stride LDS rows: X(row) = ((row>>1)^(row>>3))&3.
__device__ __forceinline__ int swz(int row, int chunk) {  // elem offset of 8-elem chunk
    return row * 32 + (((chunk ^ ((row >> 1) ^ (row >> 3))) & 3) << 3);
}

__global__ __launch_bounds__(256) void attn_mfma(
    const ushort_t* __restrict__ kb,
    const ushort_t* __restrict__ vb,
    const ushort_t* __restrict__ qb,
    float* __restrict__ out)
{
    const int tid  = threadIdx.x;
    const int wid  = tid >> 6;
    const int lane = tid & 63;
    const int fr   = lane & 15;     // fragment row (nq / m / f)
    const int fq   = lane >> 4;     // fragment k-chunk
    const size_t tb = (size_t)blockIdx.x * 4 + wid;

    // per-wave private LDS: P [32 nq][32 m] u16 + Vt [32 f][32 m] u16 (2KB each)
    __shared__ __align__(16) ushort_t lds[4][2048];
    ushort_t* Pw = lds[wid];
    ushort_t* Vt = lds[wid] + 1024;

    // zero once (pad regions m>=24 / nq>=24 must stay 0; never written later)
    #pragma unroll
    for (int i = 0; i < 4; ++i)
        reinterpret_cast<uint4*>(lds[wid])[lane + i * 64] = (uint4){0, 0, 0, 0};

    const ushort_t* qt = qb + tb * HNF;
    const ushort_t* kt = kb + tb * HNF;
    const ushort_t* vt = vb + tb * HNF;
    float* outp = out + tb * ND;

    const float scale = 0.17677669529663687f;  // 1/sqrt(32)
    const bool colok = fr < 8;                 // mt=1 valid cols (m=16..23)

    for (int h = 0; h < H_; ++h) {
        const ushort_t* qh = qt + h * 768;
        const ushort_t* kh = kt + h * 768;
        const ushort_t* vh = vt + h * 768;

        // --- Q/K fragments direct from global (row-clamped for pad tiles) ---
        bf16x8 qa[2], ka[2];
        #pragma unroll
        for (int t = 0; t < 2; ++t) {
            int rq = t * 16 + fr; rq = rq < 24 ? rq : 23;
            qa[t] = *reinterpret_cast<const bf16x8*>(qh + rq * 32 + fq * 8);
            ka[t] = *reinterpret_cast<const bf16x8*>(kh + rq * 32 + fq * 8);
        }

        // --- stage V transposed into LDS: Vt[f][m] = V[m][f] ---
        {
            const int m = lane >> 2, q = lane & 3;
            const uint4 vv = *reinterpret_cast<const uint4*>(vh + m * 32 + q * 8);
            #pragma unroll
            for (int j = 0; j < 8; ++j) {
                const int f = q * 8 + j;
                Vt[swz(f, m >> 3) + (m & 7)] = reinterpret_cast<const ushort_t*>(&vv)[j];
            }
            if (lane < 32) {
                const int m2 = 16 + (lane >> 2), q2 = lane & 3;
                const uint4 v2 = *reinterpret_cast<const uint4*>(vh + m2 * 32 + q2 * 8);
                #pragma unroll
                for (int j = 0; j < 8; ++j) {
                    const int f = q2 * 8 + j;
                    Vt[swz(f, m2 >> 3) + (m2 & 7)] = reinterpret_cast<const ushort_t*>(&v2)[j];
                }
            }
        }

        // --- S = Q K^T: 2x2 MFMA tiles ---
        f32x4 S[2][2];
        #pragma unroll
        for (int a = 0; a < 2; ++a)
            #pragma unroll
            for (int b = 0; b < 2; ++b)
                S[a][b] = __builtin_amdgcn_mfma_f32_16x16x32_bf16(
                    qa[a], ka[b], (f32x4){0.f, 0.f, 0.f, 0.f}, 0, 0, 0);

        // --- softmax over m (rows spread: row = (lane>>4)*4+r, cols = lanes) ---
        float inv[2][4];
        #pragma unroll
        for (int t = 0; t < 2; ++t) {
            const int rowbase = t * 16 + fq * 4;
            float e0[4], e1[4];
            #pragma unroll
            for (int r = 0; r < 4; ++r) {
                const float a = S[t][0][r] * scale;
                const float b = colok ? S[t][1][r] * scale : -1e30f;
                float mx = fmaxf(a, b);
                #pragma unroll
                for (int off = 1; off < 16; off <<= 1)
                    mx = fmaxf(mx, __shfl_xor(mx, off));
                e0[r] = __expf(a - mx);
                e1[r] = colok ? __expf(b - mx) : 0.f;
                float sm = e0[r] + e1[r];
                #pragma unroll
                for (int off = 1; off < 16; off <<= 1)
                    sm += __shfl_xor(sm, off);
                inv[t][r] = 1.f / sm;
            }
            // write P (unnormalized bf16; rows >=24 and cols >=24 stay zero)
            #pragma unroll
            for (int r = 0; r < 4; ++r) {
                const int row = rowbase + r;
                if (row < 24) {
                    Pw[swz(row, fr >> 3) + (fr & 7)] = f2b(e0[r]);
                    if (colok) {
                        const int c1 = 16 + fr;
                        Pw[swz(row, c1 >> 3) + (c1 & 7)] = f2b(e1[r]);
                    }
                }
            }
        }

        // --- PV: O[nq][f] = sum_m P[nq][m] V[m][f] ---
        bf16x8 pa[2], vbf[2];
        #pragma unroll
        for (int t = 0; t < 2; ++t)
            pa[t] = *reinterpret_cast<const bf16x8*>(&Pw[swz(t * 16 + fr, fq)]);
        #pragma unroll
        for (int t = 0; t < 2; ++t)
            vbf[t] = *reinterpret_cast<const bf16x8*>(&Vt[swz(t * 16 + fr, fq)]);

        f32x4 O[2][2];
        #pragma unroll
        for (int a = 0; a < 2; ++a)
            #pragma unroll
            for (int b = 0; b < 2; ++b)
                O[a][b] = __builtin_amdgcn_mfma_f32_16x16x32_bf16(
                    pa[a], vbf[b], (f32x4){0.f, 0.f, 0.f, 0.f}, 0, 0, 0);

        // --- store (normalize here; same lane holds inv for its rows) ---
        #pragma unroll
        for (int a = 0; a < 2; ++a)
            #pragma unroll
            for (int r = 0; r < 4; ++r) {
                const int row = a * 16 + fq * 4 + r;
                if (row < 24) {
                    outp[row * D_ + h * F_ + fr]      = O[a][0][r] * inv[a][r];
                    outp[row * D_ + h * F_ + 16 + fr] = O[a][1][r] * inv[a][r];
                }
            }
    }
}

extern "C" void kernel_launch(void* const* d_in, const int* in_sizes, int n_in,
                              void* d_out, int out_size, void* d_ws, size_t ws_size,
                              hipStream_t stream) {
    const float* x  = (const float*)d_in[0];
    const float* Wk = (const float*)d_in[1];
    const float* bk = (const float*)d_in[2];
    const float* Wv = (const float*)d_in[3];
    const float* bv = (const float*)d_in[4];
    const float* Wq = (const float*)d_in[5];
    const float* bq = (const float*)d_in[6];
    float* out = (float*)d_out;

    const size_t qkv_elems = (size_t)TB * HNF;
    const size_t need = qkv_elems * 2ull * 3ull;
    if (ws_size < need) fprintf(stderr, "ws too small: %zu < %zu\n", ws_size, need);
    ushort_t* kbuf = (ushort_t*)d_ws;
    ushort_t* vbuf = kbuf + qkv_elems;
    ushort_t* qbuf = vbuf + qkv_elems;

    ushort_t* Bprep = (ushort_t*)d_out;
    float*    biasp = (float*)((char*)d_out + 24ull * 8 * 24576 * 2);

    prep_weights<<<(24 * 8 * 4 * 768 + 255) / 256, 256, 0, stream>>>(Wk, Wv, Wq, Bprep);
    prep_bias<<<(24 * 768 + 255) / 256, 256, 0, stream>>>(bk, bv, bq, biasp);
    proj_mfma<<<dim3(256, 24), 256, 0, stream>>>(x, Bprep, biasp, kbuf, vbuf, qbuf);
    attn_mfma<<<TB / 4, 256, 0, stream>>>(kbuf, vbuf, qbuf, out);
}

// Round 4
// 339.564 us; speedup vs baseline: 12.7980x; 1.2014x over previous
//
#include <hip/hip_runtime.h>
#include <hip/hip_bf16.h>
#include <cstdio>

#define TB  8192
#define N_  24
#define D_  256
#define H_  8
#define F_  32
#define ND  6144      // N_*D_
#define HNF 6144      // H_*N_*F_

typedef unsigned short u16;
typedef __attribute__((ext_vector_type(8))) _Float16 f16x8;
typedef __attribute__((ext_vector_type(8))) short bf16x8;
typedef __attribute__((ext_vector_type(4))) float f32x4;

__device__ __forceinline__ u16 f2b(float f) {
    unsigned int u = __float_as_uint(f);
    return (u16)((u + 0x7FFFu + ((u >> 16) & 1u)) >> 16);
}
__device__ __forceinline__ float b2f(u16 s) {
    return __uint_as_float(((unsigned int)s) << 16);
}
__device__ __forceinline__ u16 f2h(float f) {
    _Float16 h = (_Float16)f;
    u16 u; __builtin_memcpy(&u, &h, 2); return u;
}

// ---------- prep: weights -> fp16, layout [n][kt][g(48)][fq(4)][fr(16)][8] ----------
// chunk (n,kt,g,fq,fr) holds col = g*16+fr, k = kt*32+fq*8 .. +7
__global__ __launch_bounds__(256) void prep_weights(
    const float* __restrict__ Wk, const float* __restrict__ Wv,
    const float* __restrict__ Wq, u16* __restrict__ Bp)
{
    const int idx = blockIdx.x * 256 + threadIdx.x;   // 0 .. 589823
    if (idx >= 24 * 8 * 48 * 64) return;
    const int fr = idx & 15;
    const int fq = (idx >> 4) & 3;
    const int g  = (idx >> 6) % 48;
    const int kt = (idx / (64 * 48)) % 8;
    const int n  = idx / (64 * 48 * 8);
    const int col = g * 16 + fr;
    const int d0  = kt * 32 + fq * 8;
    const int c   = col & 255;
    const float* src;
    if (col < 256)      src = Wk + (size_t)c * 256 + d0;
    else if (col < 512) src = Wv + (size_t)c * 256 + d0;
    else {
        const int h = c >> 5, f = c & 31;
        src = Wq + ((size_t)(h * 24 + n) * 32 + f) * 256 + d0;
    }
    __align__(16) u16 out[8];
    #pragma unroll
    for (int j = 0; j < 8; ++j) out[j] = f2h(src[j]);
    *reinterpret_cast<uint4*>(Bp + (size_t)idx * 8) =
        *reinterpret_cast<const uint4*>(out);
}

__global__ __launch_bounds__(256) void prep_bias(
    const float* __restrict__ bk, const float* __restrict__ bv,
    const float* __restrict__ bq, float* __restrict__ biasp)
{
    const int idx = blockIdx.x * 256 + threadIdx.x;
    if (idx >= 24 * 768) return;
    const int col = idx % 768, n = idx / 768;
    const int c = col & 255;
    float v;
    if (col < 256)      v = bk[c];
    else if (col < 512) v = bv[c];
    else { const int h = c >> 5, f = c & 31; v = bq[(h * 24 + n) * 32 + f]; }
    biasp[n * 768 + col] = v;
}

// ---------- proj v3: fp16 MFMA, BM=64 x BN=768, B direct global->VGPR ----------
__global__ __launch_bounds__(512, 2) void proj_mfma(
    const float* __restrict__ x,
    const u16* __restrict__ Bp,
    const float* __restrict__ biasp,
    u16* __restrict__ kb, u16* __restrict__ vb, u16* __restrict__ qb)
{
    // XCD-aware swizzle: n = 3 joints per XCD -> B slice (~1.2 MB) stays L2-hot
    const int lin  = blockIdx.x;                 // 0..3071
    const int n    = (lin & 7) * 3 + ((lin >> 3) >> 7);
    const int mblk = (lin >> 3) & 127;
    const int tb0  = mblk * 64;
    const int tid  = threadIdx.x;
    const int wc   = tid >> 6;                   // wave = col group (96 cols)
    const int lane = tid & 63;
    const int fr   = lane & 15, fq = lane >> 4;

    // LDS: A dbuf 2x2048 u16 (4KB) during loop; 32x768 u16 (48KB) epilogue
    __shared__ __align__(16) u16 smem[24576];

    // A staging indices
    const int arow = tid >> 3;                   // 0..63
    const int aq   = tid & 7;                    // float4 within 32-k
    const int ach  = aq >> 1, ahalf = aq & 1;
    const float* xsrc = x + (size_t)(tb0 + arow) * ND + n * D_ + aq * 4;
    const int awr = (((arow >> 4) * 4 + ach) * 16 + ((arow & 15) ^ ach)) * 8 + ahalf * 4;

    const u16* Bn = Bp + (size_t)n * 8 * 48 * 512;   // this joint's B

    f32x4 acc[4][6];
    #pragma unroll
    for (int t = 0; t < 4; ++t)
        #pragma unroll
        for (int j = 0; j < 6; ++j) acc[t][j] = (f32x4){0.f, 0.f, 0.f, 0.f};

    f16x8 bA[6], bB[6];

    // prologue: kt=0 A + B
    {
        const float4 xa = *reinterpret_cast<const float4*>(xsrc);
        const u16* bsrc = Bn + ((size_t)wc * 6) * 512 + lane * 8;
        #pragma unroll
        for (int j = 0; j < 6; ++j)
            bA[j] = *reinterpret_cast<const f16x8*>(bsrc + j * 512);
        ushort4 hv;
        hv.x = f2h(xa.x); hv.y = f2h(xa.y); hv.z = f2h(xa.z); hv.w = f2h(xa.w);
        *reinterpret_cast<ushort4*>(&smem[awr]) = hv;
    }

    #pragma unroll
    for (int kt = 0; kt < 8; ++kt) {
        __syncthreads();
        // A fragments from LDS (buf kt&1)
        f16x8 afr[4];
        #pragma unroll
        for (int t = 0; t < 4; ++t)
            afr[t] = *reinterpret_cast<const f16x8*>(
                &smem[(kt & 1) * 2048 + ((t * 4 + fq) * 16 + (fr ^ fq)) * 8]);

        // prefetch next K-step: B -> regs, A -> reg (covered by MFMA phase)
        float4 xn;
        if (kt < 7) {
            const u16* bsrc = Bn + ((size_t)(kt + 1) * 48 + wc * 6) * 512 + lane * 8;
            #pragma unroll
            for (int j = 0; j < 6; ++j)
                ((kt & 1) ? bA : bB)[j] = *reinterpret_cast<const f16x8*>(bsrc + j * 512);
            xn = *reinterpret_cast<const float4*>(xsrc + (kt + 1) * 32);
        }

        const f16x8* bc = (kt & 1) ? bB : bA;
        #pragma unroll
        for (int j = 0; j < 6; ++j)
            #pragma unroll
            for (int t = 0; t < 4; ++t)
                acc[t][j] = __builtin_amdgcn_mfma_f32_16x16x32_f16(
                    afr[t], bc[j], acc[t][j], 0, 0, 0);

        if (kt < 7) {
            ushort4 hv;
            hv.x = f2h(xn.x); hv.y = f2h(xn.y); hv.z = f2h(xn.z); hv.w = f2h(xn.w);
            *reinterpret_cast<ushort4*>(&smem[((kt + 1) & 1) * 2048 + awr]) = hv;
        }
    }

    // ---- epilogue: 2 passes of 32 rows through swizzled LDS, bf16 out ----
    char* outc = (char*)smem;
    #pragma unroll
    for (int p = 0; p < 2; ++p) {
        __syncthreads();
        #pragma unroll
        for (int tt = 0; tt < 2; ++tt) {
            const int t = p * 2 + tt;
            #pragma unroll
            for (int j = 0; j < 6; ++j) {
                const int col = wc * 96 + j * 16 + fr;
                const float bs = biasp[n * 768 + col];
                #pragma unroll
                for (int r = 0; r < 4; ++r) {
                    const int rl = tt * 16 + fq * 4 + r;
                    *reinterpret_cast<u16*>(outc + rl * 1536 +
                        ((col * 2) ^ (((rl >> 2) & 7) << 4))) = f2b(acc[t][j][r] + bs);
                }
            }
        }
        __syncthreads();
        #pragma unroll
        for (int i = 0; i < 6; ++i) {
            const int id  = i * 512 + tid;       // 0..3071
            const int rl  = id / 96;
            const int c   = id % 96;             // 16B chunk
            const uint4 v = *reinterpret_cast<const uint4*>(
                outc + rl * 1536 + ((c * 16) ^ (((rl >> 2) & 7) << 4)));
            const int col0 = c * 8;
            const int kind = col0 >> 8;
            const int cc   = col0 & 255;
            const int h    = cc >> 5, f0 = cc & 31;
            u16* dst = (kind == 0) ? kb : (kind == 1) ? vb : qb;
            const size_t di = (size_t)(tb0 + p * 32 + rl) * HNF + h * (N_ * F_) + n * F_ + f0;
            *reinterpret_cast<uint4*>(&dst[di]) = v;
        }
    }
}

// ---------------- attention: MFMA, one wave per tb, barrier-free ----------------
__device__ __forceinline__ int swz(int row, int chunk) {
    return row * 32 + (((chunk ^ ((row >> 1) ^ (row >> 3))) & 3) << 3);
}

__global__ __launch_bounds__(256) void attn_mfma(
    const u16* __restrict__ kb,
    const u16* __restrict__ vb,
    const u16* __restrict__ qb,
    float* __restrict__ out)
{
    const int tid  = threadIdx.x;
    const int wid  = tid >> 6;
    const int lane = tid & 63;
    const int fr   = lane & 15;
    const int fq   = lane >> 4;
    const size_t tb = (size_t)blockIdx.x * 4 + wid;

    __shared__ __align__(16) u16 lds[4][2048];
    u16* Pw = lds[wid];
    u16* Vt = lds[wid] + 1024;

    #pragma unroll
    for (int i = 0; i < 4; ++i)
        reinterpret_cast<uint4*>(lds[wid])[lane + i * 64] = (uint4){0, 0, 0, 0};

    const u16* qt = qb + tb * HNF;
    const u16* kt = kb + tb * HNF;
    const u16* vt = vb + tb * HNF;
    float* outp = out + tb * ND;

    const float scale = 0.17677669529663687f;
    const bool colok = fr < 8;

    for (int h = 0; h < H_; ++h) {
        const u16* qh = qt + h * 768;
        const u16* kh = kt + h * 768;
        const u16* vh = vt + h * 768;

        bf16x8 qa[2], ka[2];
        #pragma unroll
        for (int t = 0; t < 2; ++t) {
            int rq = t * 16 + fr; rq = rq < 24 ? rq : 23;
            qa[t] = *reinterpret_cast<const bf16x8*>(qh + rq * 32 + fq * 8);
            ka[t] = *reinterpret_cast<const bf16x8*>(kh + rq * 32 + fq * 8);
        }

        {
            const int m = lane >> 2, q = lane & 3;
            const uint4 vv = *reinterpret_cast<const uint4*>(vh + m * 32 + q * 8);
            #pragma unroll
            for (int j = 0; j < 8; ++j) {
                const int f = q * 8 + j;
                Vt[swz(f, m >> 3) + (m & 7)] = reinterpret_cast<const u16*>(&vv)[j];
            }
            if (lane < 32) {
                const int m2 = 16 + (lane >> 2), q2 = lane & 3;
                const uint4 v2 = *reinterpret_cast<const uint4*>(vh + m2 * 32 + q2 * 8);
                #pragma unroll
                for (int j = 0; j < 8; ++j) {
                    const int f = q2 * 8 + j;
                    Vt[swz(f, m2 >> 3) + (m2 & 7)] = reinterpret_cast<const u16*>(&v2)[j];
                }
            }
        }

        f32x4 S[2][2];
        #pragma unroll
        for (int a = 0; a < 2; ++a)
            #pragma unroll
            for (int b = 0; b < 2; ++b)
                S[a][b] = __builtin_amdgcn_mfma_f32_16x16x32_bf16(
                    qa[a], ka[b], (f32x4){0.f, 0.f, 0.f, 0.f}, 0, 0, 0);

        float inv[2][4];
        #pragma unroll
        for (int t = 0; t < 2; ++t) {
            const int rowbase = t * 16 + fq * 4;
            float e0[4], e1[4];
            #pragma unroll
            for (int r = 0; r < 4; ++r) {
                const float a = S[t][0][r] * scale;
                const float b = colok ? S[t][1][r] * scale : -1e30f;
                float mx = fmaxf(a, b);
                #pragma unroll
                for (int off = 1; off < 16; off <<= 1)
                    mx = fmaxf(mx, __shfl_xor(mx, off));
                e0[r] = __expf(a - mx);
                e1[r] = colok ? __expf(b - mx) : 0.f;
                float sm = e0[r] + e1[r];
                #pragma unroll
                for (int off = 1; off < 16; off <<= 1)
                    sm += __shfl_xor(sm, off);
                inv[t][r] = 1.f / sm;
            }
            #pragma unroll
            for (int r = 0; r < 4; ++r) {
                const int row = rowbase + r;
                if (row < 24) {
                    Pw[swz(row, fr >> 3) + (fr & 7)] = f2b(e0[r]);
                    if (colok) {
                        const int c1 = 16 + fr;
                        Pw[swz(row, c1 >> 3) + (c1 & 7)] = f2b(e1[r]);
                    }
                }
            }
        }

        bf16x8 pa[2], vbf[2];
        #pragma unroll
        for (int t = 0; t < 2; ++t)
            pa[t] = *reinterpret_cast<const bf16x8*>(&Pw[swz(t * 16 + fr, fq)]);
        #pragma unroll
        for (int t = 0; t < 2; ++t)
            vbf[t] = *reinterpret_cast<const bf16x8*>(&Vt[swz(t * 16 + fr, fq)]);

        f32x4 O[2][2];
        #pragma unroll
        for (int a = 0; a < 2; ++a)
            #pragma unroll
            for (int b = 0; b < 2; ++b)
                O[a][b] = __builtin_amdgcn_mfma_f32_16x16x32_bf16(
                    pa[a], vbf[b], (f32x4){0.f, 0.f, 0.f, 0.f}, 0, 0, 0);

        #pragma unroll
        for (int a = 0; a < 2; ++a)
            #pragma unroll
            for (int r = 0; r < 4; ++r) {
                const int row = a * 16 + fq * 4 + r;
                if (row < 24) {
                    outp[row * D_ + h * F_ + fr]      = O[a][0][r] * inv[a][r];
                    outp[row * D_ + h * F_ + 16 + fr] = O[a][1][r] * inv[a][r];
                }
            }
    }
}

extern "C" void kernel_launch(void* const* d_in, const int* in_sizes, int n_in,
                              void* d_out, int out_size, void* d_ws, size_t ws_size,
                              hipStream_t stream) {
    const float* x  = (const float*)d_in[0];
    const float* Wk = (const float*)d_in[1];
    const float* bk = (const float*)d_in[2];
    const float* Wv = (const float*)d_in[3];
    const float* bv = (const float*)d_in[4];
    const float* Wq = (const float*)d_in[5];
    const float* bq = (const float*)d_in[6];
    float* out = (float*)d_out;

    const size_t qkv_elems = (size_t)TB * HNF;
    const size_t need = qkv_elems * 2ull * 3ull;
    if (ws_size < need) fprintf(stderr, "ws too small: %zu < %zu\n", ws_size, need);
    u16* kbuf = (u16*)d_ws;
    u16* vbuf = kbuf + qkv_elems;
    u16* qbuf = vbuf + qkv_elems;

    // Bp (9.4 MB fp16) + biasp at head of d_out; attn overwrites all of d_out later
    u16*   Bp    = (u16*)d_out;
    float* biasp = (float*)((char*)d_out + (size_t)24 * 8 * 48 * 512 * 2);

    prep_weights<<<2304, 256, 0, stream>>>(Wk, Wv, Wq, Bp);
    prep_bias<<<(24 * 768 + 255) / 256, 256, 0, stream>>>(bk, bv, bq, biasp);
    proj_mfma<<<3072, 512, 0, stream>>>(x, Bp, biasp, kbuf, vbuf, qbuf);
    attn_mfma<<<TB / 4, 256, 0, stream>>>(kbuf, vbuf, qbuf, out);
}